// Round 1
// 1079.123 us; speedup vs baseline: 1.0899x; 1.0899x over previous
//
#include <hip/hip_runtime.h>
#include <hip/hip_fp16.h>

// Problem constants: B=32, N=4096, C=768, K=8
#define M_TOKENS (32*4096)
#define C_DIM 768
#define K_OUT 8

typedef _Float16 f16x8 __attribute__((ext_vector_type(8)));
typedef float f32x4 __attribute__((ext_vector_type(4)));

__device__ __forceinline__ void gl2lds16(const void* g, void* l) {
    __builtin_amdgcn_global_load_lds((const __attribute__((address_space(1))) void*)g,
                                     (__attribute__((address_space(3))) void*)l, 16, 0, 0);
}

__device__ __forceinline__ float gelu_exact(float x) {
    return 0.5f * x * (1.0f + erff(x * 0.70710678118654752440f));
}

// ---- prep_w1: w1t[n][k] = f16(gamma[k] * W1[k][n])  (transpose + gamma fold) ----
__global__ __launch_bounds__(256) void prep_w1(const float* __restrict__ w1,
                                               const float* __restrict__ gamma,
                                               _Float16* __restrict__ w1t) {
    __shared__ float t[64][65];
    const int k0 = blockIdx.x * 64, n0 = blockIdx.y * 64;
    const int c = threadIdx.x & 63, r4 = threadIdx.x >> 6;
#pragma unroll
    for (int p = 0; p < 16; ++p) {
        const int r = p*4 + r4;
        t[r][c] = w1[(size_t)(k0 + r)*C_DIM + n0 + c];
    }
    __syncthreads();
    const float g = gamma[k0 + c];
#pragma unroll
    for (int p = 0; p < 16; ++p) {
        const int n = p*4 + r4;
        w1t[(size_t)(n0 + n)*C_DIM + k0 + c] = (_Float16)(t[c][n] * g);
    }
}

// ---- prep_b1: b1p[n] = b1[n] + sum_k beta[k]*W1[k][n]; 12 blocks, 4-way k-split ----
__global__ __launch_bounds__(256) void prep_b1(const float* __restrict__ w1,
                                               const float* __restrict__ beta,
                                               const float* __restrict__ b1,
                                               float* __restrict__ b1p) {
    __shared__ float red[256];
    const int nl = threadIdx.x & 63;
    const int n = blockIdx.x*64 + nl;
    const int part = threadIdx.x >> 6;
    float s = 0.f;
    for (int k = part*192; k < part*192 + 192; ++k)
        s += beta[k] * w1[(size_t)k*C_DIM + n];
    red[threadIdx.x] = s;
    __syncthreads();
    if (part == 0)
        b1p[n] = b1[n] + red[nl] + red[nl+64] + red[nl+128] + red[nl+192];
}

// ================== NEW PATH: precomputed normalized f16 x ==================

// ---- xnorm: per token compute LN stats and write xn = f16((x-mu)*rs) ----
__global__ __launch_bounds__(256) void xnorm_kernel(const float* __restrict__ x,
                                                    _Float16* __restrict__ xn) {
    const int row = blockIdx.x*4 + (threadIdx.x >> 6);
    const int lane = threadIdx.x & 63;
    const float4* xr = (const float4*)(x + (size_t)row * C_DIM);
    float4 v[3];
    float s = 0.f, s2 = 0.f;
#pragma unroll
    for (int i = 0; i < 3; ++i) {
        v[i] = xr[lane + i*64];
        s  += v[i].x + v[i].y + v[i].z + v[i].w;
        s2 += v[i].x*v[i].x + v[i].y*v[i].y + v[i].z*v[i].z + v[i].w*v[i].w;
    }
#pragma unroll
    for (int m = 1; m < 64; m <<= 1) { s += __shfl_xor(s, m); s2 += __shfl_xor(s2, m); }
    const float mu = s * (1.f/768.f);
    const float rs = rsqrtf(s2 * (1.f/768.f) - mu*mu + 1e-5f);
    const float nm = -mu * rs;
    _Float16* xo = xn + (size_t)row * C_DIM;
#pragma unroll
    for (int i = 0; i < 3; ++i) {
        union { _Float16 h[4]; uint2 uu; } pk;
        pk.h[0] = (_Float16)(v[i].x*rs + nm);
        pk.h[1] = (_Float16)(v[i].y*rs + nm);
        pk.h[2] = (_Float16)(v[i].z*rs + nm);
        pk.h[3] = (_Float16)(v[i].w*rs + nm);
        *(uint2*)(xo + (size_t)(lane + i*64)*4) = pk.uu;
    }
}

// ---- GEMM1 (h = GELU(xn@W1t'+b1')) pure f16 + fused GEMM2 (partial logits) ----
// grid (6 n-blocks, 1024 m-blocks), 256 threads, tile 128x128, BK=64.
__global__ __launch_bounds__(256) void gemm1_h_kernel(const _Float16* __restrict__ xn,
        const _Float16* __restrict__ w1t, const float* __restrict__ b1p,
        const float* __restrict__ w2, float* __restrict__ logits) {
    __shared__ __align__(16) union {
        struct { _Float16 a[128*64]; _Float16 b[128*64]; } s;   // 16K + 16K
        _Float16 ht[128*136];                                   // 34K
    } u;
    __shared__ float w2s[128*K_OUT];
    __shared__ float b1s[128];

    const int tid = threadIdx.x;
    const int wid = tid >> 6, lane = tid & 63;
    const int l15 = lane & 15, q = lane >> 4;
    const int wm = wid >> 1, wn = wid & 1;
    const int n0 = blockIdx.x * 128;   // output-col block (0..5)
    const int m0 = blockIdx.y * 128;   // token block (0..1023)

    for (int i = tid; i < 128*K_OUT; i += 256) w2s[i] = w2[(size_t)n0*K_OUT + i];
    if (tid < 128) b1s[tid] = b1p[n0 + tid];

    f32x4 acc[4][4] = {};  // acc[nt][mt]

    for (int kt = 0; kt < 12; ++kt) {
        const int k0 = kt * 64;
        // stage A: xn f16 tile 128x64 (1024 16B chunks), swizzle ^(row&7)
#pragma unroll
        for (int i = 0; i < 4; ++i) {
            const int L = i*256 + tid;
            const int row = L >> 3, j = (L & 7) ^ (row & 7);
            gl2lds16(xn + (size_t)(m0 + row)*C_DIM + k0 + j*8,
                     &u.s.a[(i*256 + wid*64)*8]);
        }
        // stage B: w1t f16 tile 128x64
#pragma unroll
        for (int i = 0; i < 4; ++i) {
            const int L = i*256 + tid;
            const int row = L >> 3, j = (L & 7) ^ (row & 7);
            gl2lds16(w1t + (size_t)(n0 + row)*C_DIM + k0 + j*8,
                     &u.s.b[(i*256 + wid*64)*8]);
        }
        __syncthreads();
#pragma unroll
        for (int kk = 0; kk < 2; ++kk) {
            f16x8 af[4], bfr[4];
#pragma unroll
            for (int nt = 0; nt < 4; ++nt) {            // A: w1t rows = outcols
                const int row = wn*64 + nt*16 + l15;
                const int j = (kk*4 + q) ^ (row & 7);
                af[nt] = *(const f16x8*)&u.s.b[row*64 + j*8];
            }
#pragma unroll
            for (int mt = 0; mt < 4; ++mt) {            // B: xn rows = tokens
                const int row = wm*64 + mt*16 + l15;
                const int j = (kk*4 + q) ^ (row & 7);
                bfr[mt] = *(const f16x8*)&u.s.a[row*64 + j*8];
            }
#pragma unroll
            for (int nt = 0; nt < 4; ++nt)
#pragma unroll
                for (int mt = 0; mt < 4; ++mt)
                    acc[nt][mt] = __builtin_amdgcn_mfma_f32_16x16x32_f16(
                        af[nt], bfr[mt], acc[nt][mt], 0, 0, 0);
        }
        __syncthreads();
    }

    // epilogue: bias + exact GELU -> LDS h tile [token][col] f16 (stride 136)
#pragma unroll
    for (int nt = 0; nt < 4; ++nt) {
#pragma unroll
        for (int mt = 0; mt < 4; ++mt) {
            const int token = wm*64 + mt*16 + l15;
            const int nl = wn*64 + nt*16 + q*4;
            union { _Float16 h[4]; uint2 uu; } pk;
#pragma unroll
            for (int r = 0; r < 4; ++r)
                pk.h[r] = (_Float16)gelu_exact(acc[nt][mt][r] + b1s[nl + r]);
            *(uint2*)&u.ht[token*136 + nl] = pk.uu;
        }
    }
    __syncthreads();

    // fused GEMM2: logits[token][k] += h_tile @ W2[n0:n0+128][:]
    f16x8 wf[4];
#pragma unroll
    for (int ks = 0; ks < 4; ++ks) {
        f16x8 t;
#pragma unroll
        for (int j = 0; j < 8; ++j) {
            const int kd = ks*32 + q*8 + j;
            t[j] = (_Float16)((l15 < K_OUT) ? w2s[kd*K_OUT + l15] : 0.f);
        }
        wf[ks] = t;
    }
#pragma unroll
    for (int t2 = 0; t2 < 2; ++t2) {
        const int tt = wid*2 + t2;
        f32x4 p = {};
#pragma unroll
        for (int ks = 0; ks < 4; ++ks) {
            const f16x8 a = *(const f16x8*)&u.ht[(tt*16 + l15)*136 + ks*32 + q*8];
            p = __builtin_amdgcn_mfma_f32_16x16x32_f16(a, wf[ks], p, 0, 0, 0);
        }
        if (l15 < K_OUT) {
#pragma unroll
            for (int r = 0; r < 4; ++r)
                atomicAdd(&logits[(size_t)(m0 + tt*16 + q*4 + r)*K_OUT + l15], p[r]);
        }
    }
}

// ================== FALLBACK PATH (small workspace): prior kernels ==================

__global__ __launch_bounds__(256) void stats_kernel(const float* __restrict__ x,
                                                    float2* __restrict__ stats) {
    const int row = blockIdx.x*4 + (threadIdx.x >> 6);
    const int lane = threadIdx.x & 63;
    const float4* xr = (const float4*)(x + (size_t)row * C_DIM);
    float s = 0.f, s2 = 0.f;
#pragma unroll
    for (int i = 0; i < 3; ++i) {
        const float4 v = xr[lane + i*64];
        s  += v.x + v.y + v.z + v.w;
        s2 += v.x*v.x + v.y*v.y + v.z*v.z + v.w*v.w;
    }
#pragma unroll
    for (int m = 1; m < 64; m <<= 1) { s += __shfl_xor(s, m); s2 += __shfl_xor(s2, m); }
    if (lane == 0) {
        const float mu = s * (1.f/768.f);
        const float rs = rsqrtf(s2 * (1.f/768.f) - mu*mu + 1e-5f);
        stats[row] = make_float2(rs, -mu*rs);
    }
}

__global__ __launch_bounds__(256) void gemm1_ln_kernel(const float* __restrict__ x,
        const float2* __restrict__ stats, const _Float16* __restrict__ w1t,
        const float* __restrict__ b1p, const float* __restrict__ w2,
        float* __restrict__ logits) {
    __shared__ __align__(16) union {
        struct { float a[128*64]; _Float16 b[128*64]; } s;   // 32K + 16K
        _Float16 ht[128*136];                                 // 34K
    } u;
    __shared__ float w2s[128*K_OUT];
    __shared__ float b1s[128];

    const int tid = threadIdx.x;
    const int wid = tid >> 6, lane = tid & 63;
    const int l15 = lane & 15, q = lane >> 4;
    const int wm = wid >> 1, wn = wid & 1;
    const int n0 = blockIdx.x * 128;
    const int m0 = blockIdx.y * 128;

    for (int i = tid; i < 128*K_OUT; i += 256) w2s[i] = w2[(size_t)n0*K_OUT + i];
    if (tid < 128) b1s[tid] = b1p[n0 + tid];

    float rsL[4], nmL[4];
#pragma unroll
    for (int mt = 0; mt < 4; ++mt) {
        const float2 st = stats[m0 + wm*64 + mt*16 + l15];
        rsL[mt] = st.x; nmL[mt] = st.y;
    }

    f32x4 acc[4][4] = {};

    for (int kt = 0; kt < 12; ++kt) {
        const int k0 = kt * 64;
#pragma unroll
        for (int i = 0; i < 8; ++i) {
            const int L = i*256 + tid;
            const int row = L >> 4, g = (L & 15) ^ (row & 15);
            gl2lds16(x + (size_t)(m0 + row)*C_DIM + k0 + g*4,
                     &u.s.a[(i*256 + wid*64)*4]);
        }
#pragma unroll
        for (int i = 0; i < 4; ++i) {
            const int L = i*256 + tid;
            const int row = L >> 3, j = (L & 7) ^ (row & 7);
            gl2lds16(w1t + (size_t)(n0 + row)*C_DIM + k0 + j*8,
                     &u.s.b[(i*256 + wid*64)*8]);
        }
        __syncthreads();
#pragma unroll
        for (int kk = 0; kk < 2; ++kk) {
            f16x8 af[4], bfr[4];
#pragma unroll
            for (int nt = 0; nt < 4; ++nt) {
                const int row = wn*64 + nt*16 + l15;
                const int j = (kk*4 + q) ^ (row & 7);
                af[nt] = *(const f16x8*)&u.s.b[row*64 + j*8];
            }
#pragma unroll
            for (int mt = 0; mt < 4; ++mt) {
                const int row = wm*64 + mt*16 + l15;
                const int gc = kk*8 + q*2;
                const int c0 = gc ^ (row & 15), c1 = (gc + 1) ^ (row & 15);
                const f32x4 v0 = *(const f32x4*)&u.s.a[row*64 + c0*4];
                const f32x4 v1 = *(const f32x4*)&u.s.a[row*64 + c1*4];
                f16x8 t;
#pragma unroll
                for (int j = 0; j < 4; ++j) {
                    t[j]   = (_Float16)(v0[j]*rsL[mt] + nmL[mt]);
                    t[4+j] = (_Float16)(v1[j]*rsL[mt] + nmL[mt]);
                }
                bfr[mt] = t;
            }
#pragma unroll
            for (int nt = 0; nt < 4; ++nt)
#pragma unroll
                for (int mt = 0; mt < 4; ++mt)
                    acc[nt][mt] = __builtin_amdgcn_mfma_f32_16x16x32_f16(
                        af[nt], bfr[mt], acc[nt][mt], 0, 0, 0);
        }
        __syncthreads();
    }

#pragma unroll
    for (int nt = 0; nt < 4; ++nt) {
#pragma unroll
        for (int mt = 0; mt < 4; ++mt) {
            const int token = wm*64 + mt*16 + l15;
            const int nl = wn*64 + nt*16 + q*4;
            union { _Float16 h[4]; uint2 uu; } pk;
#pragma unroll
            for (int r = 0; r < 4; ++r)
                pk.h[r] = (_Float16)gelu_exact(acc[nt][mt][r] + b1s[nl + r]);
            *(uint2*)&u.ht[token*136 + nl] = pk.uu;
        }
    }
    __syncthreads();

    f16x8 wf[4];
#pragma unroll
    for (int ks = 0; ks < 4; ++ks) {
        f16x8 t;
#pragma unroll
        for (int j = 0; j < 8; ++j) {
            const int kd = ks*32 + q*8 + j;
            t[j] = (_Float16)((l15 < K_OUT) ? w2s[kd*K_OUT + l15] : 0.f);
        }
        wf[ks] = t;
    }
#pragma unroll
    for (int t2 = 0; t2 < 2; ++t2) {
        const int tt = wid*2 + t2;
        f32x4 p = {};
#pragma unroll
        for (int ks = 0; ks < 4; ++ks) {
            const f16x8 a = *(const f16x8*)&u.ht[(tt*16 + l15)*136 + ks*32 + q*8];
            p = __builtin_amdgcn_mfma_f32_16x16x32_f16(a, wf[ks], p, 0, 0, 0);
        }
        if (l15 < K_OUT) {
#pragma unroll
            for (int r = 0; r < 4; ++r)
                atomicAdd(&logits[(size_t)(m0 + tt*16 + q*4 + r)*K_OUT + l15], p[r]);
        }
    }
}

// ---- softmax over tokens per (b,k), IN-PLACE on logits; b2 shift-invariant ----
__global__ __launch_bounds__(256) void softmax_kernel(float* p) {
    const int b = blockIdx.x >> 3, k = blockIdx.x & 7;
    const size_t base = ((size_t)b*4096)*K_OUT + k;
    const int tid = threadIdx.x;
    float r[16];
    float mx = -1e30f;
#pragma unroll
    for (int i = 0; i < 16; ++i) {
        r[i] = p[base + (size_t)(tid + i*256)*K_OUT];
        mx = fmaxf(mx, r[i]);
    }
#pragma unroll
    for (int m = 1; m < 64; m <<= 1) mx = fmaxf(mx, __shfl_xor(mx, m));
    __shared__ float redm[4], reds[4];
    if ((tid & 63) == 0) redm[tid >> 6] = mx;
    __syncthreads();
    mx = fmaxf(fmaxf(redm[0], redm[1]), fmaxf(redm[2], redm[3]));
    float s = 0.f;
#pragma unroll
    for (int i = 0; i < 16; ++i) { r[i] = __expf(r[i] - mx); s += r[i]; }
#pragma unroll
    for (int m = 1; m < 64; m <<= 1) s += __shfl_xor(s, m);
    if ((tid & 63) == 0) reds[tid >> 6] = s;
    __syncthreads();
    s = reds[0] + reds[1] + reds[2] + reds[3];
    const float inv = 1.f / s;
#pragma unroll
    for (int i = 0; i < 16; ++i)
        p[base + (size_t)(tid + i*256)*K_OUT] = r[i] * inv;
}

// ---- pooling: out[b][k][c] = sum_n attn[b][n][k] * x[b][n][c] ----
__global__ __launch_bounds__(192) void pool_kernel(const float* __restrict__ x,
        const float* __restrict__ attn, float* __restrict__ out) {
    const int b = blockIdx.x, nc = blockIdx.y;
    const int t0 = nc * 128;
    __shared__ float as_[128*K_OUT];
    for (int i = threadIdx.x; i < 128*K_OUT; i += 192)
        as_[i] = attn[((size_t)b*4096 + t0)*K_OUT + i];
    __syncthreads();
    const int c = threadIdx.x * 4;
    float acc[K_OUT][4] = {};
    const float* xb = x + ((size_t)b*4096 + t0)*C_DIM + c;
    for (int i = 0; i < 128; ++i) {
        const float4 xv = *(const float4*)(xb + (size_t)i*C_DIM);
#pragma unroll
        for (int k = 0; k < K_OUT; ++k) {
            const float a = as_[i*K_OUT + k];
            acc[k][0] += a*xv.x; acc[k][1] += a*xv.y;
            acc[k][2] += a*xv.z; acc[k][3] += a*xv.w;
        }
    }
#pragma unroll
    for (int k = 0; k < K_OUT; ++k)
#pragma unroll
        for (int j = 0; j < 4; ++j)
            atomicAdd(&out[((size_t)b*K_OUT + k)*C_DIM + c + j], acc[k][j]);
}

extern "C" void kernel_launch(void* const* d_in, const int* in_sizes, int n_in,
                              void* d_out, int out_size, void* d_ws, size_t ws_size,
                              hipStream_t stream) {
    const float* x     = (const float*)d_in[0];
    const float* gamma = (const float*)d_in[1];
    const float* beta  = (const float*)d_in[2];
    const float* W1    = (const float*)d_in[3];
    const float* b1    = (const float*)d_in[4];
    const float* W2    = (const float*)d_in[5];
    // d_in[6] = b2: constant along softmax (token) axis -> cancels; unused.
    (void)in_sizes; (void)n_in;

    float* out = (float*)d_out;
    char* ws = (char*)d_ws;

    // New path needs: xn (f16 M x C) + w1t + b1p + logits
    const size_t XN_BYTES  = (size_t)M_TOKENS * C_DIM * 2;        // 201,326,592
    const size_t NEED_NEW  = XN_BYTES + 1179648 + 4096 + 4194304; // ~206.7 MB

    if (ws_size >= NEED_NEW) {
        _Float16* xn     = (_Float16*)ws;
        _Float16* w1t    = (_Float16*)(ws + XN_BYTES);
        float*    b1p    = (float*)(ws + XN_BYTES + 1179648);
        float*    logits = (float*)(ws + XN_BYTES + 1179648 + 4096);

        (void)hipMemsetAsync(logits, 0, (size_t)M_TOKENS * K_OUT * 4, stream);
        (void)hipMemsetAsync(d_out, 0, (size_t)out_size * sizeof(float), stream);

        prep_w1<<<dim3(12, 12), 256, 0, stream>>>(W1, gamma, w1t);
        prep_b1<<<12, 256, 0, stream>>>(W1, beta, b1, b1p);
        xnorm_kernel<<<M_TOKENS/4, 256, 0, stream>>>(x, xn);
        gemm1_h_kernel<<<dim3(6, 1024), 256, 0, stream>>>(xn, w1t, b1p, W2, logits);
        softmax_kernel<<<256, 256, 0, stream>>>(logits);
        pool_kernel<<<dim3(32, 32), 192, 0, stream>>>(x, logits, out);
    } else {
        // fallback: prior in-GEMM LN-fused pipeline (~6.4 MB workspace)
        float2*   stats  = (float2*)ws;                       // 1,048,576 B
        _Float16* w1t    = (_Float16*)(ws + 1048576);         // 1,179,648 B
        float*    b1p    = (float*)(ws + 2228224);            //     4,096 B (pad)
        float*    logits = (float*)(ws + 2232320);            // 4,194,304 B

        (void)hipMemsetAsync(logits, 0, (size_t)M_TOKENS * K_OUT * 4, stream);
        (void)hipMemsetAsync(d_out, 0, (size_t)out_size * sizeof(float), stream);

        prep_w1<<<dim3(12, 12), 256, 0, stream>>>(W1, gamma, w1t);
        prep_b1<<<12, 256, 0, stream>>>(W1, beta, b1, b1p);
        stats_kernel<<<M_TOKENS/4, 256, 0, stream>>>(x, stats);
        gemm1_ln_kernel<<<dim3(6, 1024), 256, 0, stream>>>(x, stats, w1t, b1p, W2, logits);
        softmax_kernel<<<256, 256, 0, stream>>>(logits);
        pool_kernel<<<dim3(32, 32), 192, 0, stream>>>(x, logits, out);
    }
}

// Round 2
// 1005.868 us; speedup vs baseline: 1.1692x; 1.0728x over previous
//
#include <hip/hip_runtime.h>
#include <hip/hip_fp16.h>

// Problem constants: B=32, N=4096, C=768, K=8
#define M_TOKENS (32*4096)
#define C_DIM 768
#define K_OUT 8

typedef _Float16 f16x8 __attribute__((ext_vector_type(8)));
typedef float f32x4 __attribute__((ext_vector_type(4)));

__device__ __forceinline__ void gl2lds16(const void* g, void* l) {
    __builtin_amdgcn_global_load_lds((const __attribute__((address_space(1))) void*)g,
                                     (__attribute__((address_space(3))) void*)l, 16, 0, 0);
}

// Branch-free exact-GELU: erf via Abramowitz-Stegun 7.1.26 (|eps|<=1.5e-7 abs),
// ~15 VALU + 1 trans vs libm erff's ~60 branchy ops. Error is ~3 orders below
// the fp16 rounding applied to h, so output accuracy is unchanged.
__device__ __forceinline__ float gelu_fast(float x) {
    const float z  = x * 0.70710678118654752440f;   // x/sqrt(2)
    const float az = fabsf(z);
    const float t  = __builtin_amdgcn_rcpf(1.0f + 0.3275911f * az);
    float p = 1.061405429f;
    p = p * t - 1.453152027f;
    p = p * t + 1.421413741f;
    p = p * t - 0.284496736f;
    p = p * t + 0.254829592f;
    p = p * t;
    const float e = __expf(-az * az);
    const float erf_abs = 1.0f - p * e;
    const float erf_z = copysignf(erf_abs, z);
    return 0.5f * x * (1.0f + erf_z);
}

// ---- prep_w1: w1t[n][k] = f16(gamma[k] * W1[k][n])  (transpose + gamma fold) ----
__global__ __launch_bounds__(256) void prep_w1(const float* __restrict__ w1,
                                               const float* __restrict__ gamma,
                                               _Float16* __restrict__ w1t) {
    __shared__ float t[64][65];
    const int k0 = blockIdx.x * 64, n0 = blockIdx.y * 64;
    const int c = threadIdx.x & 63, r4 = threadIdx.x >> 6;
#pragma unroll
    for (int p = 0; p < 16; ++p) {
        const int r = p*4 + r4;
        t[r][c] = w1[(size_t)(k0 + r)*C_DIM + n0 + c];
    }
    __syncthreads();
    const float g = gamma[k0 + c];
#pragma unroll
    for (int p = 0; p < 16; ++p) {
        const int n = p*4 + r4;
        w1t[(size_t)(n0 + n)*C_DIM + k0 + c] = (_Float16)(t[c][n] * g);
    }
}

// ---- prep_b1: b1p[n] = b1[n] + sum_k beta[k]*W1[k][n]; 12 blocks, 4-way k-split ----
__global__ __launch_bounds__(256) void prep_b1(const float* __restrict__ w1,
                                               const float* __restrict__ beta,
                                               const float* __restrict__ b1,
                                               float* __restrict__ b1p) {
    __shared__ float red[256];
    const int nl = threadIdx.x & 63;
    const int n = blockIdx.x*64 + nl;
    const int part = threadIdx.x >> 6;
    float s = 0.f;
    for (int k = part*192; k < part*192 + 192; ++k)
        s += beta[k] * w1[(size_t)k*C_DIM + n];
    red[threadIdx.x] = s;
    __syncthreads();
    if (part == 0)
        b1p[n] = b1[n] + red[nl] + red[nl+64] + red[nl+128] + red[nl+192];
}

// ---- xnorm: per token compute LN stats and write xn = f16((x-mu)*rs) ----
// 2 rows per wave, interleaved: doubles outstanding loads and pipelines the
// two independent shuffle-reduce chains.
__global__ __launch_bounds__(256) void xnorm_kernel(const float* __restrict__ x,
                                                    _Float16* __restrict__ xn) {
    const int row0 = blockIdx.x*8 + (threadIdx.x >> 6)*2;
    const int lane = threadIdx.x & 63;
    const float4* xr0 = (const float4*)(x + (size_t)row0 * C_DIM);
    const float4* xr1 = (const float4*)(x + (size_t)(row0 + 1) * C_DIM);
    float4 v0[3], v1[3];
#pragma unroll
    for (int i = 0; i < 3; ++i) { v0[i] = xr0[lane + i*64]; v1[i] = xr1[lane + i*64]; }
    float sa = 0.f, s2a = 0.f, sb = 0.f, s2b = 0.f;
#pragma unroll
    for (int i = 0; i < 3; ++i) {
        sa  += v0[i].x + v0[i].y + v0[i].z + v0[i].w;
        s2a += v0[i].x*v0[i].x + v0[i].y*v0[i].y + v0[i].z*v0[i].z + v0[i].w*v0[i].w;
        sb  += v1[i].x + v1[i].y + v1[i].z + v1[i].w;
        s2b += v1[i].x*v1[i].x + v1[i].y*v1[i].y + v1[i].z*v1[i].z + v1[i].w*v1[i].w;
    }
#pragma unroll
    for (int m = 1; m < 64; m <<= 1) {
        sa += __shfl_xor(sa, m); s2a += __shfl_xor(s2a, m);
        sb += __shfl_xor(sb, m); s2b += __shfl_xor(s2b, m);
    }
    const float mua = sa * (1.f/768.f);
    const float rsa = rsqrtf(s2a * (1.f/768.f) - mua*mua + 1e-5f);
    const float nma = -mua * rsa;
    const float mub = sb * (1.f/768.f);
    const float rsb = rsqrtf(s2b * (1.f/768.f) - mub*mub + 1e-5f);
    const float nmb = -mub * rsb;
    _Float16* xo0 = xn + (size_t)row0 * C_DIM;
    _Float16* xo1 = xn + (size_t)(row0 + 1) * C_DIM;
#pragma unroll
    for (int i = 0; i < 3; ++i) {
        union { _Float16 h[4]; uint2 uu; } pk;
        pk.h[0] = (_Float16)(v0[i].x*rsa + nma);
        pk.h[1] = (_Float16)(v0[i].y*rsa + nma);
        pk.h[2] = (_Float16)(v0[i].z*rsa + nma);
        pk.h[3] = (_Float16)(v0[i].w*rsa + nma);
        *(uint2*)(xo0 + (size_t)(lane + i*64)*4) = pk.uu;
        pk.h[0] = (_Float16)(v1[i].x*rsb + nmb);
        pk.h[1] = (_Float16)(v1[i].y*rsb + nmb);
        pk.h[2] = (_Float16)(v1[i].z*rsb + nmb);
        pk.h[3] = (_Float16)(v1[i].w*rsb + nmb);
        *(uint2*)(xo1 + (size_t)(lane + i*64)*4) = pk.uu;
    }
}

// ---- GEMM1 (h = GELU(xn@W1t'+b1')) pure f16 + fused GEMM2 (partial logits) ----
// grid 6144 linear blocks (6 n-blocks x 1024 m-blocks), T1 XCD swizzle so all
// 6 n-blocks sharing a token panel land on the same XCD/L2.
__global__ __launch_bounds__(256) void gemm1_h_kernel(const _Float16* __restrict__ xn,
        const _Float16* __restrict__ w1t, const float* __restrict__ b1p,
        const float* __restrict__ w2, float* __restrict__ logits) {
    __shared__ __align__(16) union {
        struct { _Float16 a[128*64]; _Float16 b[128*64]; } s;   // 16K + 16K
        _Float16 ht[128*136];                                   // 34K
    } u;
    __shared__ float w2s[128*K_OUT];
    __shared__ float b1s[128];

    const int tid = threadIdx.x;
    const int wid = tid >> 6, lane = tid & 63;
    const int l15 = lane & 15, q = lane >> 4;
    const int wm = wid >> 1, wn = wid & 1;

    // T1: grid = 6144 = 8 XCDs * 768. HW round-robins blockIdx % 8 across XCDs;
    // remap so each XCD owns 128 consecutive token panels (all 6 n-blocks each).
    const int L = blockIdx.y * 6 + blockIdx.x;
    const int swz = (L & 7) * 768 + (L >> 3);
    const int n0 = (swz % 6) * 128;   // output-col block (0..5)
    const int m0 = (swz / 6) * 128;   // token block (0..1023)

    for (int i = tid; i < 128*K_OUT; i += 256) w2s[i] = w2[(size_t)n0*K_OUT + i];
    if (tid < 128) b1s[tid] = b1p[n0 + tid];

    f32x4 acc[4][4] = {};  // acc[nt][mt]

    for (int kt = 0; kt < 12; ++kt) {
        const int k0 = kt * 64;
        // stage A: xn f16 tile 128x64 (1024 16B chunks), swizzle ^(row&7)
#pragma unroll
        for (int i = 0; i < 4; ++i) {
            const int Li = i*256 + tid;
            const int row = Li >> 3, j = (Li & 7) ^ (row & 7);
            gl2lds16(xn + (size_t)(m0 + row)*C_DIM + k0 + j*8,
                     &u.s.a[(i*256 + wid*64)*8]);
        }
        // stage B: w1t f16 tile 128x64
#pragma unroll
        for (int i = 0; i < 4; ++i) {
            const int Li = i*256 + tid;
            const int row = Li >> 3, j = (Li & 7) ^ (row & 7);
            gl2lds16(w1t + (size_t)(n0 + row)*C_DIM + k0 + j*8,
                     &u.s.b[(i*256 + wid*64)*8]);
        }
        __syncthreads();
#pragma unroll
        for (int kk = 0; kk < 2; ++kk) {
            f16x8 af[4], bfr[4];
#pragma unroll
            for (int nt = 0; nt < 4; ++nt) {            // A: w1t rows = outcols
                const int row = wn*64 + nt*16 + l15;
                const int j = (kk*4 + q) ^ (row & 7);
                af[nt] = *(const f16x8*)&u.s.b[row*64 + j*8];
            }
#pragma unroll
            for (int mt = 0; mt < 4; ++mt) {            // B: xn rows = tokens
                const int row = wm*64 + mt*16 + l15;
                const int j = (kk*4 + q) ^ (row & 7);
                bfr[mt] = *(const f16x8*)&u.s.a[row*64 + j*8];
            }
#pragma unroll
            for (int nt = 0; nt < 4; ++nt)
#pragma unroll
                for (int mt = 0; mt < 4; ++mt)
                    acc[nt][mt] = __builtin_amdgcn_mfma_f32_16x16x32_f16(
                        af[nt], bfr[mt], acc[nt][mt], 0, 0, 0);
        }
        __syncthreads();
    }

    // epilogue: bias + fast exact GELU -> LDS h tile [token][col] f16 (stride 136)
#pragma unroll
    for (int nt = 0; nt < 4; ++nt) {
#pragma unroll
        for (int mt = 0; mt < 4; ++mt) {
            const int token = wm*64 + mt*16 + l15;
            const int nl = wn*64 + nt*16 + q*4;
            union { _Float16 h[4]; uint2 uu; } pk;
#pragma unroll
            for (int r = 0; r < 4; ++r)
                pk.h[r] = (_Float16)gelu_fast(acc[nt][mt][r] + b1s[nl + r]);
            *(uint2*)&u.ht[token*136 + nl] = pk.uu;
        }
    }
    __syncthreads();

    // fused GEMM2: logits[token][k] += h_tile @ W2[n0:n0+128][:]
    f16x8 wf[4];
#pragma unroll
    for (int ks = 0; ks < 4; ++ks) {
        f16x8 t;
#pragma unroll
        for (int j = 0; j < 8; ++j) {
            const int kd = ks*32 + q*8 + j;
            t[j] = (_Float16)((l15 < K_OUT) ? w2s[kd*K_OUT + l15] : 0.f);
        }
        wf[ks] = t;
    }
#pragma unroll
    for (int t2 = 0; t2 < 2; ++t2) {
        const int tt = wid*2 + t2;
        f32x4 p = {};
#pragma unroll
        for (int ks = 0; ks < 4; ++ks) {
            const f16x8 a = *(const f16x8*)&u.ht[(tt*16 + l15)*136 + ks*32 + q*8];
            p = __builtin_amdgcn_mfma_f32_16x16x32_f16(a, wf[ks], p, 0, 0, 0);
        }
        if (l15 < K_OUT) {
#pragma unroll
            for (int r = 0; r < 4; ++r)
                atomicAdd(&logits[(size_t)(m0 + tt*16 + q*4 + r)*K_OUT + l15], p[r]);
        }
    }
}

// ================== FALLBACK PATH (small workspace): prior kernels ==================

__global__ __launch_bounds__(256) void stats_kernel(const float* __restrict__ x,
                                                    float2* __restrict__ stats) {
    const int row = blockIdx.x*4 + (threadIdx.x >> 6);
    const int lane = threadIdx.x & 63;
    const float4* xr = (const float4*)(x + (size_t)row * C_DIM);
    float s = 0.f, s2 = 0.f;
#pragma unroll
    for (int i = 0; i < 3; ++i) {
        const float4 v = xr[lane + i*64];
        s  += v.x + v.y + v.z + v.w;
        s2 += v.x*v.x + v.y*v.y + v.z*v.z + v.w*v.w;
    }
#pragma unroll
    for (int m = 1; m < 64; m <<= 1) { s += __shfl_xor(s, m); s2 += __shfl_xor(s2, m); }
    if (lane == 0) {
        const float mu = s * (1.f/768.f);
        const float rs = rsqrtf(s2 * (1.f/768.f) - mu*mu + 1e-5f);
        stats[row] = make_float2(rs, -mu*rs);
    }
}

__global__ __launch_bounds__(256) void gemm1_ln_kernel(const float* __restrict__ x,
        const float2* __restrict__ stats, const _Float16* __restrict__ w1t,
        const float* __restrict__ b1p, const float* __restrict__ w2,
        float* __restrict__ logits) {
    __shared__ __align__(16) union {
        struct { float a[128*64]; _Float16 b[128*64]; } s;
        _Float16 ht[128*136];
    } u;
    __shared__ float w2s[128*K_OUT];
    __shared__ float b1s[128];

    const int tid = threadIdx.x;
    const int wid = tid >> 6, lane = tid & 63;
    const int l15 = lane & 15, q = lane >> 4;
    const int wm = wid >> 1, wn = wid & 1;
    const int n0 = blockIdx.x * 128;
    const int m0 = blockIdx.y * 128;

    for (int i = tid; i < 128*K_OUT; i += 256) w2s[i] = w2[(size_t)n0*K_OUT + i];
    if (tid < 128) b1s[tid] = b1p[n0 + tid];

    float rsL[4], nmL[4];
#pragma unroll
    for (int mt = 0; mt < 4; ++mt) {
        const float2 st = stats[m0 + wm*64 + mt*16 + l15];
        rsL[mt] = st.x; nmL[mt] = st.y;
    }

    f32x4 acc[4][4] = {};

    for (int kt = 0; kt < 12; ++kt) {
        const int k0 = kt * 64;
#pragma unroll
        for (int i = 0; i < 8; ++i) {
            const int L = i*256 + tid;
            const int row = L >> 4, g = (L & 15) ^ (row & 15);
            gl2lds16(x + (size_t)(m0 + row)*C_DIM + k0 + g*4,
                     &u.s.a[(i*256 + wid*64)*4]);
        }
#pragma unroll
        for (int i = 0; i < 4; ++i) {
            const int L = i*256 + tid;
            const int row = L >> 3, j = (L & 7) ^ (row & 7);
            gl2lds16(w1t + (size_t)(n0 + row)*C_DIM + k0 + j*8,
                     &u.s.b[(i*256 + wid*64)*8]);
        }
        __syncthreads();
#pragma unroll
        for (int kk = 0; kk < 2; ++kk) {
            f16x8 af[4], bfr[4];
#pragma unroll
            for (int nt = 0; nt < 4; ++nt) {
                const int row = wn*64 + nt*16 + l15;
                const int j = (kk*4 + q) ^ (row & 7);
                af[nt] = *(const f16x8*)&u.s.b[row*64 + j*8];
            }
#pragma unroll
            for (int mt = 0; mt < 4; ++mt) {
                const int row = wm*64 + mt*16 + l15;
                const int gc = kk*8 + q*2;
                const int c0 = gc ^ (row & 15), c1 = (gc + 1) ^ (row & 15);
                const f32x4 v0 = *(const f32x4*)&u.s.a[row*64 + c0*4];
                const f32x4 v1 = *(const f32x4*)&u.s.a[row*64 + c1*4];
                f16x8 t;
#pragma unroll
                for (int j = 0; j < 4; ++j) {
                    t[j]   = (_Float16)(v0[j]*rsL[mt] + nmL[mt]);
                    t[4+j] = (_Float16)(v1[j]*rsL[mt] + nmL[mt]);
                }
                bfr[mt] = t;
            }
#pragma unroll
            for (int nt = 0; nt < 4; ++nt)
#pragma unroll
                for (int mt = 0; mt < 4; ++mt)
                    acc[nt][mt] = __builtin_amdgcn_mfma_f32_16x16x32_f16(
                        af[nt], bfr[mt], acc[nt][mt], 0, 0, 0);
        }
        __syncthreads();
    }

#pragma unroll
    for (int nt = 0; nt < 4; ++nt) {
#pragma unroll
        for (int mt = 0; mt < 4; ++mt) {
            const int token = wm*64 + mt*16 + l15;
            const int nl = wn*64 + nt*16 + q*4;
            union { _Float16 h[4]; uint2 uu; } pk;
#pragma unroll
            for (int r = 0; r < 4; ++r)
                pk.h[r] = (_Float16)gelu_fast(acc[nt][mt][r] + b1s[nl + r]);
            *(uint2*)&u.ht[token*136 + nl] = pk.uu;
        }
    }
    __syncthreads();

    f16x8 wf[4];
#pragma unroll
    for (int ks = 0; ks < 4; ++ks) {
        f16x8 t;
#pragma unroll
        for (int j = 0; j < 8; ++j) {
            const int kd = ks*32 + q*8 + j;
            t[j] = (_Float16)((l15 < K_OUT) ? w2s[kd*K_OUT + l15] : 0.f);
        }
        wf[ks] = t;
    }
#pragma unroll
    for (int t2 = 0; t2 < 2; ++t2) {
        const int tt = wid*2 + t2;
        f32x4 p = {};
#pragma unroll
        for (int ks = 0; ks < 4; ++ks) {
            const f16x8 a = *(const f16x8*)&u.ht[(tt*16 + l15)*136 + ks*32 + q*8];
            p = __builtin_amdgcn_mfma_f32_16x16x32_f16(a, wf[ks], p, 0, 0, 0);
        }
        if (l15 < K_OUT) {
#pragma unroll
            for (int r = 0; r < 4; ++r)
                atomicAdd(&logits[(size_t)(m0 + tt*16 + q*4 + r)*K_OUT + l15], p[r]);
        }
    }
}

// ---- softmax over tokens per (b,k), IN-PLACE on logits; b2 shift-invariant ----
__global__ __launch_bounds__(256) void softmax_kernel(float* p) {
    const int b = blockIdx.x >> 3, k = blockIdx.x & 7;
    const size_t base = ((size_t)b*4096)*K_OUT + k;
    const int tid = threadIdx.x;
    float r[16];
    float mx = -1e30f;
#pragma unroll
    for (int i = 0; i < 16; ++i) {
        r[i] = p[base + (size_t)(tid + i*256)*K_OUT];
        mx = fmaxf(mx, r[i]);
    }
#pragma unroll
    for (int m = 1; m < 64; m <<= 1) mx = fmaxf(mx, __shfl_xor(mx, m));
    __shared__ float redm[4], reds[4];
    if ((tid & 63) == 0) redm[tid >> 6] = mx;
    __syncthreads();
    mx = fmaxf(fmaxf(redm[0], redm[1]), fmaxf(redm[2], redm[3]));
    float s = 0.f;
#pragma unroll
    for (int i = 0; i < 16; ++i) { r[i] = __expf(r[i] - mx); s += r[i]; }
#pragma unroll
    for (int m = 1; m < 64; m <<= 1) s += __shfl_xor(s, m);
    if ((tid & 63) == 0) reds[tid >> 6] = s;
    __syncthreads();
    s = reds[0] + reds[1] + reds[2] + reds[3];
    const float inv = 1.f / s;
#pragma unroll
    for (int i = 0; i < 16; ++i)
        p[base + (size_t)(tid + i*256)*K_OUT] = r[i] * inv;
}

// ---- pooling: out[b][k][c] = sum_n attn[b][n][k] * x[b][n][c] ----
__global__ __launch_bounds__(192) void pool_kernel(const float* __restrict__ x,
        const float* __restrict__ attn, float* __restrict__ out) {
    const int b = blockIdx.x, nc = blockIdx.y;
    const int t0 = nc * 128;
    __shared__ float as_[128*K_OUT];
    for (int i = threadIdx.x; i < 128*K_OUT; i += 192)
        as_[i] = attn[((size_t)b*4096 + t0)*K_OUT + i];
    __syncthreads();
    const int c = threadIdx.x * 4;
    float acc[K_OUT][4] = {};
    const float* xb = x + ((size_t)b*4096 + t0)*C_DIM + c;
#pragma unroll 4
    for (int i = 0; i < 128; ++i) {
        const float4 xv = *(const float4*)(xb + (size_t)i*C_DIM);
#pragma unroll
        for (int k = 0; k < K_OUT; ++k) {
            const float a = as_[i*K_OUT + k];
            acc[k][0] += a*xv.x; acc[k][1] += a*xv.y;
            acc[k][2] += a*xv.z; acc[k][3] += a*xv.w;
        }
    }
#pragma unroll
    for (int k = 0; k < K_OUT; ++k)
#pragma unroll
        for (int j = 0; j < 4; ++j)
            atomicAdd(&out[((size_t)b*K_OUT + k)*C_DIM + c + j], acc[k][j]);
}

extern "C" void kernel_launch(void* const* d_in, const int* in_sizes, int n_in,
                              void* d_out, int out_size, void* d_ws, size_t ws_size,
                              hipStream_t stream) {
    const float* x     = (const float*)d_in[0];
    const float* gamma = (const float*)d_in[1];
    const float* beta  = (const float*)d_in[2];
    const float* W1    = (const float*)d_in[3];
    const float* b1    = (const float*)d_in[4];
    const float* W2    = (const float*)d_in[5];
    // d_in[6] = b2: constant along softmax (token) axis -> cancels; unused.
    (void)in_sizes; (void)n_in;

    float* out = (float*)d_out;
    char* ws = (char*)d_ws;

    const size_t XN_BYTES  = (size_t)M_TOKENS * C_DIM * 2;        // 201,326,592
    const size_t NEED_NEW  = XN_BYTES + 1179648 + 4096 + 4194304; // ~206.7 MB

    if (ws_size >= NEED_NEW) {
        _Float16* xn     = (_Float16*)ws;
        _Float16* w1t    = (_Float16*)(ws + XN_BYTES);
        float*    b1p    = (float*)(ws + XN_BYTES + 1179648);
        float*    logits = (float*)(ws + XN_BYTES + 1179648 + 4096);

        (void)hipMemsetAsync(logits, 0, (size_t)M_TOKENS * K_OUT * 4, stream);
        (void)hipMemsetAsync(d_out, 0, (size_t)out_size * sizeof(float), stream);

        prep_w1<<<dim3(12, 12), 256, 0, stream>>>(W1, gamma, w1t);
        prep_b1<<<12, 256, 0, stream>>>(W1, beta, b1, b1p);
        xnorm_kernel<<<M_TOKENS/8, 256, 0, stream>>>(x, xn);
        gemm1_h_kernel<<<dim3(6, 1024), 256, 0, stream>>>(xn, w1t, b1p, W2, logits);
        softmax_kernel<<<256, 256, 0, stream>>>(logits);
        pool_kernel<<<dim3(32, 32), 192, 0, stream>>>(x, logits, out);
    } else {
        // fallback: prior in-GEMM LN-fused pipeline (~6.4 MB workspace)
        float2*   stats  = (float2*)ws;
        _Float16* w1t    = (_Float16*)(ws + 1048576);
        float*    b1p    = (float*)(ws + 2228224);
        float*    logits = (float*)(ws + 2232320);

        (void)hipMemsetAsync(logits, 0, (size_t)M_TOKENS * K_OUT * 4, stream);
        (void)hipMemsetAsync(d_out, 0, (size_t)out_size * sizeof(float), stream);

        prep_w1<<<dim3(12, 12), 256, 0, stream>>>(W1, gamma, w1t);
        prep_b1<<<12, 256, 0, stream>>>(W1, beta, b1, b1p);
        stats_kernel<<<M_TOKENS/4, 256, 0, stream>>>(x, stats);
        gemm1_ln_kernel<<<dim3(6, 1024), 256, 0, stream>>>(x, stats, w1t, b1p, W2, logits);
        softmax_kernel<<<256, 256, 0, stream>>>(logits);
        pool_kernel<<<dim3(32, 32), 192, 0, stream>>>(x, logits, out);
    }
}